// Round 2
// baseline (398.209 us; speedup 1.0000x reference)
//
#include <hip/hip_runtime.h>
#include <hip/hip_bf16.h>
#include <stdint.h>

// Problem constants
#define B_  2
#define S_  2048
#define D_  1024
#define H_  16
#define HD_ 64
#define M_  (B_*S_)   // 4096

typedef __bf16 bf16;
typedef bf16  bf16x8 __attribute__((ext_vector_type(8)));
typedef bf16  bf16x4 __attribute__((ext_vector_type(4)));
typedef float f32x4  __attribute__((ext_vector_type(4)));

__device__ __forceinline__ f32x4 mfma16(bf16x8 a, bf16x8 b, f32x4 c) {
    return __builtin_amdgcn_mfma_f32_16x16x32_bf16(a, b, c, 0, 0, 0);
}

// async global->LDS, 16B per lane; LDS dest = wave-uniform base + lane*16
__device__ __forceinline__ void gload_lds16(const bf16* g, bf16* l) {
    auto* gp = reinterpret_cast<__attribute__((address_space(1))) uint32_t*>(
        reinterpret_cast<uintptr_t>(const_cast<bf16*>(g)));
    auto* lp = reinterpret_cast<__attribute__((address_space(3))) uint32_t*>(
        reinterpret_cast<uintptr_t>(l));
    __builtin_amdgcn_global_load_lds(gp, lp, 16, 0, 0);
}

// ---------------------------------------------------------------------------
// fp32 -> bf16 conversion: grid.y selects tensor {x(4M), Wq, Wk, Wv, Wp (1M ea)}
// ---------------------------------------------------------------------------
__global__ __launch_bounds__(256) void k_convert(
        const float* __restrict__ x,
        const float* __restrict__ wq, const float* __restrict__ wk,
        const float* __restrict__ wv, const float* __restrict__ wp,
        bf16* __restrict__ xb,
        bf16* __restrict__ wqb, bf16* __restrict__ wkb,
        bf16* __restrict__ wvb, bf16* __restrict__ wpb) {
    const int y = blockIdx.y;
    const float* src = (y == 0) ? x : (y == 1) ? wq : (y == 2) ? wk
                     : (y == 3) ? wv : wp;
    bf16* dst        = (y == 0) ? xb : (y == 1) ? wqb : (y == 2) ? wkb
                     : (y == 3) ? wvb : wpb;
    const int reps = (y == 0) ? 4 : 1;   // x is 4M elements, weights 1M
    const int idx = blockIdx.x * 256 + threadIdx.x;   // 1024 blocks -> 1M elems/rep
    for (int rep = 0; rep < reps; ++rep) {
        const size_t e = (size_t)rep * (1u << 20) + (size_t)idx * 4;
        const float4 f = *(const float4*)(src + e);
        bf16x4 o;
        o[0] = (bf16)f.x; o[1] = (bf16)f.y; o[2] = (bf16)f.z; o[3] = (bf16)f.w;
        *(bf16x4*)(dst + e) = o;
    }
}

// ---------------------------------------------------------------------------
// GEMM: C[M,N] = A[M,K] * Bt[N,K]^T + bias[N], K = D_ = 1024.
// 128x128 tile, BK=32, 256 threads (4 waves, 2x2 of 64x64 per wave).
// PERM=true writes C (bf16) to [B,H,S,HD] layout (QKV); else row-major OutT.
// ---------------------------------------------------------------------------
template<bool PERM, typename OutT>
__device__ __forceinline__ void gemm_body(const bf16* __restrict__ A,
                                          const bf16* __restrict__ Bt,
                                          const float* __restrict__ bias,
                                          OutT* __restrict__ C) {
    __shared__ bf16 As[128*32];
    __shared__ bf16 Bs[128*32];
    const int K = D_;
    const int tid = threadIdx.x;
    const int w  = tid >> 6, L = tid & 63;
    const int lr = L & 15,  lq = L >> 4;
    const int tileM = blockIdx.y * 128, tileN = blockIdx.x * 128;
    const int wm = (w >> 1) * 64, wn = (w & 1) * 64;

    const f32x4 fzero = {0.f, 0.f, 0.f, 0.f};
    f32x4 acc[4][4];
#pragma unroll
    for (int i = 0; i < 4; ++i)
#pragma unroll
        for (int j = 0; j < 4; ++j) acc[i][j] = fzero;

    // staging: lane L covers row (L>>2) of its wave's 32-row slab, 16B chunk.
    // XOR-swizzle the K-chunk by (row&3) to spread LDS read banks.
    const int srow   = L >> 2;                 // 0..15
    const int schunk = (L & 3) ^ (srow & 3);   // swizzled 16B-chunk index
    const bf16* ag = A  + (size_t)(tileM + w*32 + srow) * K + schunk*8;
    const bf16* bg = Bt + (size_t)(tileN + w*32 + srow) * K + schunk*8;
    bf16* asd = &As[(w*32)*32];
    bf16* bsd = &Bs[(w*32)*32];
    const int sw = lr & 3;                     // read-side swizzle key

    for (int kt = 0; kt < K; kt += 32) {
        __syncthreads();
        gload_lds16(ag + kt,          asd);
        gload_lds16(ag + kt + 16*K,   asd + 16*32);
        gload_lds16(bg + kt,          bsd);
        gload_lds16(bg + kt + 16*K,   bsd + 16*32);
        __syncthreads();   // compiler emits vmcnt(0) drain before s_barrier

        bf16x8 af[4], bfr[4];
#pragma unroll
        for (int i = 0; i < 4; ++i)
            af[i]  = *(const bf16x8*)&As[(wm + i*16 + lr)*32 + ((lq ^ sw) * 8)];
#pragma unroll
        for (int j = 0; j < 4; ++j)
            bfr[j] = *(const bf16x8*)&Bs[(wn + j*16 + lr)*32 + ((lq ^ sw) * 8)];
#pragma unroll
        for (int i = 0; i < 4; ++i)
#pragma unroll
            for (int j = 0; j < 4; ++j)
                acc[i][j] = mfma16(af[i], bfr[j], acc[i][j]);
    }

    // epilogue: C/D layout col=lane&15, row=quad*4+reg  [m89-verified]
#pragma unroll
    for (int i = 0; i < 4; ++i) {
#pragma unroll
        for (int j = 0; j < 4; ++j) {
#pragma unroll
            for (int r = 0; r < 4; ++r) {
                const int m = tileM + wm + i*16 + lq*4 + r;
                const int n = tileN + wn + j*16 + lr;
                const float v = acc[i][j][r] + bias[n];
                if (PERM) {
                    const int b = m >> 11, s = m & (S_ - 1);
                    const int h = n >> 6,  e = n & 63;
                    C[((size_t)((b*H_ + h)*S_ + s) << 6) + e] = (OutT)v;
                } else {
                    C[(size_t)m * D_ + n] = (OutT)v;
                }
            }
        }
    }
}

__global__ __launch_bounds__(256) void k_gemm_qkv(
        const bf16* __restrict__ x,
        const bf16* __restrict__ Wq, const bf16* __restrict__ Wk, const bf16* __restrict__ Wv,
        const float* __restrict__ bq, const float* __restrict__ bk, const float* __restrict__ bv,
        bf16* __restrict__ q, bf16* __restrict__ k, bf16* __restrict__ v) {
    const int z = blockIdx.z;
    const bf16* W   = (z == 0) ? Wq : (z == 1) ? Wk : Wv;
    const float* bb = (z == 0) ? bq : (z == 1) ? bk : bv;
    bf16* out       = (z == 0) ? q  : (z == 1) ? k  : v;
    gemm_body<true, bf16>(x, W, bb, out);
}

__global__ __launch_bounds__(256) void k_gemm_proj(
        const bf16* __restrict__ A, const bf16* __restrict__ Wp,
        const float* __restrict__ bp, float* __restrict__ C) {
    gemm_body<false, float>(A, Wp, bp, C);
}

// ---------------------------------------------------------------------------
// V transpose: [bh][t][e] -> [bh][e][t], u32-pair LDS transpose (conflict-free)
// ---------------------------------------------------------------------------
__global__ __launch_bounds__(256) void k_transpose_v(const bf16* __restrict__ v,
                                                     bf16* __restrict__ vt) {
    __shared__ uint32_t T[64*33];
    const uint32_t* v32 = (const uint32_t*)v;
    uint32_t* vt32 = (uint32_t*)vt;
    const int tid = threadIdx.x;
    const int bh  = blockIdx.y;
    const int t0  = blockIdx.x * 64;
    const size_t base32 = (size_t)bh * (S_ * HD_ / 2);   // 65536 u32 per bh

#pragma unroll
    for (int it = 0; it < 8; ++it) {
        const int idx = it*256 + tid;
        const int tl = idx >> 5, ec = idx & 31;
        T[tl*33 + ec] = v32[base32 + (size_t)(t0 + tl)*(HD_/2) + ec];
    }
    __syncthreads();
#pragma unroll
    for (int it = 0; it < 8; ++it) {
        const int idx = it*256 + tid;
        const int e = idx >> 5, tc = idx & 31;
        const uint32_t a = T[(2*tc)*33   + (e >> 1)];
        const uint32_t b = T[(2*tc+1)*33 + (e >> 1)];
        const uint32_t o = (e & 1) ? ((a >> 16)      | (b & 0xffff0000u))
                                   : ((a & 0xffffu)  | (b << 16));
        vt32[base32 + (size_t)e*(S_/2) + (t0 >> 1) + tc] = o;
    }
}

// ---------------------------------------------------------------------------
// Flash attention: grid (S/64, B*H), 256 threads = 4 independent waves,
// each wave owns 16 query rows. No block barriers.
// Q,K: [bh][s][e]   Vt: [bh][e][t]   O: [B,S,D] (bf16) with col = h*64+e
// ---------------------------------------------------------------------------
__global__ __launch_bounds__(256) void k_attn(const bf16* __restrict__ Q,
                                              const bf16* __restrict__ Kg,
                                              const bf16* __restrict__ Vt,
                                              bf16* __restrict__ O) {
    __shared__ bf16 Ps[4*16*72];   // per-wave 16x64 P tile, rows padded to 72
    const int tid = threadIdx.x;
    const int w  = tid >> 6, L = tid & 63;
    const int lr = L & 15,  lq = L >> 4;
    const int bh = blockIdx.y;
    const int q0 = blockIdx.x * 64 + w * 16;
    const size_t base = (size_t)bh * S_ * HD_;
    const bf16* qp = Q  + base;
    const bf16* kp = Kg + base;
    const bf16* vp = Vt + base;    // rows of S_ elements, indexed [e][t]

    const bf16x8 qf0 = *(const bf16x8*)&qp[(q0 + lr)*HD_ + lq*8];
    const bf16x8 qf1 = *(const bf16x8*)&qp[(q0 + lr)*HD_ + 32 + lq*8];

    const f32x4 fzero = {0.f, 0.f, 0.f, 0.f};
    float m_run[4], l_run[4];
    f32x4 o_acc[4];
#pragma unroll
    for (int r = 0; r < 4; ++r) { m_run[r] = -3.0e38f; l_run[r] = 0.f; }
#pragma unroll
    for (int eb = 0; eb < 4; ++eb) o_acc[eb] = fzero;

    bf16* myP = &Ps[w * 16 * 72];

    for (int t0 = 0; t0 < S_; t0 += 64) {
        // ---- scores: S[q][t] = (Q K^T) * 0.125 ----
        f32x4 sc[4];
#pragma unroll
        for (int j = 0; j < 4; ++j) {
            const bf16* kr = &kp[(size_t)(t0 + j*16 + lr) * HD_];
            const bf16x8 kf0 = *(const bf16x8*)&kr[lq*8];
            const bf16x8 kf1 = *(const bf16x8*)&kr[32 + lq*8];
            f32x4 z = fzero;
            z = mfma16(qf0, kf0, z);
            z = mfma16(qf1, kf1, z);
            sc[j] = z * 0.125f;
        }
        // ---- online softmax (rows live on 16-lane groups) ----
        float mx[4];
#pragma unroll
        for (int r = 0; r < 4; ++r) {
            mx[r] = fmaxf(fmaxf(sc[0][r], sc[1][r]), fmaxf(sc[2][r], sc[3][r]));
            mx[r] = fmaxf(mx[r], __shfl_xor(mx[r], 1));
            mx[r] = fmaxf(mx[r], __shfl_xor(mx[r], 2));
            mx[r] = fmaxf(mx[r], __shfl_xor(mx[r], 4));
            mx[r] = fmaxf(mx[r], __shfl_xor(mx[r], 8));
        }
        float alpha[4], rs[4];
#pragma unroll
        for (int r = 0; r < 4; ++r) {
            const float mn = fmaxf(m_run[r], mx[r]);
            alpha[r] = __expf(m_run[r] - mn);
            m_run[r] = mn;
            rs[r] = 0.f;
        }
        float p[4][4];
#pragma unroll
        for (int j = 0; j < 4; ++j)
#pragma unroll
            for (int r = 0; r < 4; ++r) {
                p[j][r] = __expf(sc[j][r] - m_run[r]);
                rs[r] += p[j][r];
            }
#pragma unroll
        for (int r = 0; r < 4; ++r) {
            rs[r] += __shfl_xor(rs[r], 1);
            rs[r] += __shfl_xor(rs[r], 2);
            rs[r] += __shfl_xor(rs[r], 4);
            rs[r] += __shfl_xor(rs[r], 8);
            l_run[r] = l_run[r] * alpha[r] + rs[r];
        }
#pragma unroll
        for (int eb = 0; eb < 4; ++eb)
#pragma unroll
            for (int r = 0; r < 4; ++r) o_acc[eb][r] *= alpha[r];

        // ---- P: C-layout regs -> per-wave LDS -> A-layout frags ----
#pragma unroll
        for (int j = 0; j < 4; ++j)
#pragma unroll
            for (int r = 0; r < 4; ++r)
                myP[(lq*4 + r)*72 + j*16 + lr] = (bf16)p[j][r];

        const bf16x8 pa0 = *(const bf16x8*)&myP[lr*72 + lq*8];
        const bf16x8 pa1 = *(const bf16x8*)&myP[lr*72 + 32 + lq*8];

        // ---- O += P * V  (V^T rows give contiguous B-fragments) ----
#pragma unroll
        for (int eb = 0; eb < 4; ++eb) {
            const bf16* vr = &vp[(size_t)(eb*16 + lr) * S_ + t0];
            const bf16x8 vb0 = *(const bf16x8*)&vr[lq*8];
            const bf16x8 vb1 = *(const bf16x8*)&vr[32 + lq*8];
            o_acc[eb] = mfma16(pa0, vb0, o_acc[eb]);
            o_acc[eb] = mfma16(pa1, vb1, o_acc[eb]);
        }
    }

    // ---- epilogue: O[b, q, h*64+e] = o/l ----
    const int b = bh >> 4, h = bh & 15;
#pragma unroll
    for (int eb = 0; eb < 4; ++eb)
#pragma unroll
        for (int r = 0; r < 4; ++r) {
            const int qg = q0 + lq*4 + r;
            O[((size_t)(b*S_ + qg))*D_ + h*64 + eb*16 + lr] =
                (bf16)(o_acc[eb][r] / l_run[r]);
        }
}

// ---------------------------------------------------------------------------
extern "C" void kernel_launch(void* const* d_in, const int* in_sizes, int n_in,
                              void* d_out, int out_size, void* d_ws, size_t ws_size,
                              hipStream_t stream) {
    const float* x  = (const float*)d_in[0];
    const float* Wq = (const float*)d_in[1];
    const float* bq = (const float*)d_in[2];
    const float* Wk = (const float*)d_in[3];
    const float* bk = (const float*)d_in[4];
    const float* Wv = (const float*)d_in[5];
    const float* bv = (const float*)d_in[6];
    const float* Wp = (const float*)d_in[7];
    const float* bp = (const float*)d_in[8];
    float* out = (float*)d_out;

    // workspace layout (bf16 elements). 20M elems = 40 MB total.
    const size_t NE = (size_t)B_ * H_ * S_ * HD_;   // 4 Mi elements (8 MB bf16)
    const size_t NW = (size_t)D_ * D_;              // 1 Mi elements (2 MB bf16)
    bf16* xb  = (bf16*)d_ws;          // [0, 4M)  -- reused as vt after QKV GEMM
    bf16* wqb = xb + NE;              // [4M, 5M)
    bf16* wkb = wqb + NW;             // [5M, 6M)
    bf16* wvb = wkb + NW;             // [6M, 7M)
    bf16* wpb = wvb + NW;             // [7M, 8M)
    bf16* q_ws = wpb + NW;            // [8M, 12M)
    bf16* k_ws = q_ws + NE;           // [12M, 16M)
    bf16* v_ws = k_ws + NE;           // [16M, 20M)
    bf16* vt_ws = xb;                 // reuse x-bf16 slot (x dead after QKV)
    bf16* a_ws  = v_ws;               // reuse V slot (V dead after transpose... read via vt)

    k_convert<<<dim3(1024, 5), 256, 0, stream>>>(x, Wq, Wk, Wv, Wp,
                                                 xb, wqb, wkb, wvb, wpb);
    k_gemm_qkv<<<dim3(D_/128, M_/128, 3), 256, 0, stream>>>(
        xb, wqb, wkb, wvb, bq, bk, bv, q_ws, k_ws, v_ws);
    k_transpose_v<<<dim3(S_/64, B_*H_), 256, 0, stream>>>(v_ws, vt_ws);
    k_attn<<<dim3(S_/64, B_*H_), 256, 0, stream>>>(q_ws, k_ws, vt_ws, a_ws);
    k_gemm_proj<<<dim3(D_/128, M_/128, 1), 256, 0, stream>>>(a_ws, wpb, bp, out);
}